// Round 6
// baseline (12643.228 us; speedup 1.0000x reference)
//
#include <hip/hip_runtime.h>
#include <stdint.h>

typedef __attribute__((ext_vector_type(8))) short bf16x8;
typedef __attribute__((ext_vector_type(4))) float f32x4;
typedef unsigned short u16;

#define MFMA16(a,b,c) __builtin_amdgcn_mfma_f32_16x16x32_bf16((a),(b),(c),0,0,0)

static constexpr int T_STEPS = 256;
static constexpr int BATCH   = 2048;
static constexpr int YDIM    = 20;
static constexpr int BS      = 64;            // batch rows per group
static constexpr int NG      = 32;            // groups
static constexpr int NS      = 8;             // slices (CUs) per group
static constexpr int NWG     = NG * NS;       // 256

// ---- ws layout ----
// Weights, frag-linear, per (slice c, role, frag f): 8 x 4 x 34 x 512 u16.
//   role 0..2 = gate r/z/n:  f 0..15 Whh0 (ct*8+kt), 16..17 Wih0pad (ct), 18..33 Whh1
//   role 3    = MLP:         f 0..15 W1, 16..31 W2, 32..33 W3pad (ct)
//   frag (16x16x32 B): lane L holds W[ncol_base+(L&15)][kt*32+(L>>4)*8+j]
static constexpr int OFF_W_U   = 0;
static constexpr int W_U       = 8 * 4 * 34 * 512;        // 557056 u16
// gx1 B-frags (Wih1) for LDS residency: per slice 48 blocks (g*16+ct*8+kt)
static constexpr int OFF_X1_U  = W_U;                      // 557056
static constexpr int X1_U      = 8 * 48 * 512;             // 196608
// gather buffers (u16), per group 64x256 each
static constexpr int OFF_H0_U  = OFF_X1_U + X1_U;          // 753664
static constexpr int OFF_H1_U  = OFF_H0_U + NG * 16384;    // 1277952
static constexpr int OFF_D1_U  = OFF_H1_U + NG * 16384;    // 1802240
static constexpr int OFF_D3_U  = OFF_D1_U + NG * 16384;    // 2326528 (f32 area after, aligned)
// d3 partials: f32 [group][slice][64][32]
static constexpr size_t OFF_D3_B = (size_t)OFF_D3_U * 2;   // 4653056 bytes
static constexpr size_t D3_B     = (size_t)NG * NS * 64 * 32 * 4;  // 2097152
static constexpr size_t OFF_CT_B = OFF_D3_B + D3_B;        // 6750208
static constexpr int    CT_N     = NG * 1024;              // u32 counters

__device__ __forceinline__ u16 f2bf(float x) {
    uint32_t u = __float_as_uint(x);
    u += 0x7FFFu + ((u >> 16) & 1u);
    return (u16)(u >> 16);
}
__device__ __forceinline__ float bf2f(u16 h) {
    return __uint_as_float(((uint32_t)h) << 16);
}
__device__ __forceinline__ float sigm(float x) { return 1.0f / (1.0f + __expf(-x)); }
__device__ __forceinline__ float tanh_fast(float x) {
    float s = __expf(-2.0f * fabsf(x));
    float r = (1.0f - s) / (1.0f + s);
    return copysignf(r, x);
}
__device__ __forceinline__ f32x4 zero4() { f32x4 v = {0.f,0.f,0.f,0.f}; return v; }
__device__ __forceinline__ void pin(bf16x8& v) { asm volatile("" : "+v"(v)); }

// ---------------- prep: weights -> frag-linear; zero counters & out ----------------
__global__ void prep_kernel(const float* __restrict__ Wih0, const float* __restrict__ Whh0,
                            const float* __restrict__ Wih1, const float* __restrict__ Whh1,
                            const float* __restrict__ W1,   const float* __restrict__ W2,
                            const float* __restrict__ W3,   u16* __restrict__ ws,
                            float* __restrict__ out) {
    int tid = blockIdx.x * blockDim.x + threadIdx.x;
    int stride = gridDim.x * blockDim.x;
    if (tid == 0) out[0] = 0.0f;
    // region A: per-slice role frags
    for (int i = tid; i < W_U; i += stride) {
        int c    = i / 69632;            // 4*34*512
        int rem  = i - c * 69632;
        int role = rem / 17408;          // 34*512
        int rem2 = rem - role * 17408;
        int f = rem2 >> 9, q = rem2 & 511, L = q >> 3, j = q & 7;
        int l16 = L & 15, kq = L >> 4;
        float v = 0.0f;
        if (role < 3) {
            int ct, ncol;
            if (f < 16)      { ct = f >> 3; int kt = f & 7;  ncol = role*256 + c*32 + ct*16 + l16;
                               v = Whh0[ncol*256 + kt*32 + kq*8 + j]; }
            else if (f < 18) { ct = f - 16; ncol = role*256 + c*32 + ct*16 + l16; int kk = kq*8 + j;
                               v = (kk < YDIM) ? Wih0[ncol*YDIM + kk] : 0.0f; }
            else             { int ff = f - 18; ct = ff >> 3; int kt = ff & 7; ncol = role*256 + c*32 + ct*16 + l16;
                               v = Whh1[ncol*256 + kt*32 + kq*8 + j]; }
        } else {
            if (f < 16)      { int ct = f >> 3, kt = f & 7; int dcol = c*32 + ct*16 + l16;
                               v = W1[dcol*256 + kt*32 + kq*8 + j]; }
            else if (f < 32) { int ff = f - 16; int ct = ff >> 3, kt = ff & 7; int dcol = c*32 + ct*16 + l16;
                               v = W2[dcol*256 + kt*32 + kq*8 + j]; }
            else             { int ct = f - 32; int r3 = ct*16 + l16; int kk = kq*8 + j;
                               v = (r3 < YDIM) ? W3[r3*256 + c*32 + kk] : 0.0f; }
        }
        ws[i] = f2bf(v);
    }
    // region X1 (Wih1 frag blocks for LDS)
    for (int i = tid; i < X1_U; i += stride) {
        int c = i / 24576;               // 48*512
        int rem = i - c * 24576;
        int blk = rem >> 9, q = rem & 511, L = q >> 3, j = q & 7;
        int g = blk >> 4, ct = (blk >> 3) & 1, kt = blk & 7;
        int ncol = g*256 + c*32 + ct*16 + (L & 15);
        ws[OFF_X1_U + i] = f2bf(Wih1[ncol*256 + kt*32 + (L >> 4)*8 + j]);
    }
    // zero barrier counters
    uint32_t* ctr = (uint32_t*)((char*)ws + OFF_CT_B);
    for (int i = tid; i < CT_N; i += stride) ctr[i] = 0;
}

// ---------------- main persistent kernel ----------------
__global__ __launch_bounds__(512, 2) void rnn_main(
    const float* __restrict__ data,
    const float* __restrict__ bih0g, const float* __restrict__ bhh0g,
    const float* __restrict__ bih1g, const float* __restrict__ bhh1g,
    const float* __restrict__ b1g,  const float* __restrict__ b2g,
    const float* __restrict__ b3g,
    u16* __restrict__ ws, float* __restrict__ out)
{
    __shared__ u16  sh_h0[64][264];
    __shared__ u16  sh_h1[64][264];
    __shared__ u16  lds_wx1[48 * 512];     // gx1 B-frags (Wih1 slice), 48 KB
    __shared__ u16  sh_x[64][40];
    __shared__ u16  sh_d2[64][40];
    __shared__ float rzbuf[4096];          // gate exchange [rz][mh][ct][ml][q][lane]
    __shared__ float sh_b3[32];

    const int tid  = threadIdx.x;
    const int w    = tid >> 6;             // wave 0..7
    const int lane = tid & 63;
    const int l16  = lane & 15;
    const int kq   = lane >> 4;
    const int kq8  = kq * 8;
    const int b    = blockIdx.x;
    const int g    = b & 31;               // group (same-XCD members: b ≡ g mod 32)
    const int c    = b >> 5;               // slice 0..7
    const int mh   = w & 1;                // M-half for gate waves & MLP waves
    const bool isGate = (w < 6);
    const bool isN    = (w >= 4 && w < 6);
    const bool isRZ   = (w < 4);
    const bool isMLP  = (w >= 6);
    const int  grole  = isGate ? (w >> 1) : 3;

    u16* const h0buf = ws + OFF_H0_U + g * 16384;
    u16* const h1buf = ws + OFF_H1_U + g * 16384;
    u16* const d1buf = ws + OFF_D1_U + g * 16384;
    float* const d3p = (float*)((char*)ws + OFF_D3_B) + (size_t)g * 16384;
    uint32_t* const ctrg = (uint32_t*)((char*)ws + OFF_CT_B) + g * 1024;

    // ---- load weight fragments (role-unioned wf[34]) ----
    bf16x8 wf[34];
    {
        const u16* wp = ws + (size_t)(c * 4 + grole) * 17408;
        #pragma unroll
        for (int f = 0; f < 34; ++f) {
            wf[f] = *(const bf16x8*)(wp + f * 512 + lane * 8);
            pin(wf[f]);
        }
    }
    // ---- copy Wih1 slice frags -> LDS (48 KB) ----
    {
        const u16* src = ws + OFF_X1_U + (size_t)c * 24576;
        #pragma unroll
        for (int ii = 0; ii < 6; ++ii) {
            int o = (tid * 6 + ii) * 8;
            *(bf16x8*)&lds_wx1[o] = *(const bf16x8*)(src + o);
        }
    }
    // ---- init LDS state ----
    for (int i = tid; i < 64 * 264; i += 512) { (&sh_h0[0][0])[i] = 0; (&sh_h1[0][0])[i] = 0; }
    for (int i = tid; i < 64 * 40;  i += 512) (&sh_x[0][0])[i] = 0;
    if (tid < 32) sh_b3[tid] = (tid < YDIM) ? b3g[tid] : 0.0f;
    // stage x(0)
    for (int i = tid; i < BS * YDIM; i += 512) {
        int row = i / YDIM, col = i - row * YDIM;
        sh_x[row][col] = f2bf(data[(size_t)(g * BS + row) * YDIM + col]);
    }
    // ---- per-lane biases (role-dependent) ----
    float bp0[2] = {0,0}, bq0[2] = {0,0}, bp1[2] = {0,0}, bq1[2] = {0,0};
    #pragma unroll
    for (int ct = 0; ct < 2; ++ct) {
        const int col = c * 32 + ct * 16 + l16;
        if (isRZ) {
            const int gg = w >> 1;
            bp0[ct] = bih0g[gg*256 + col] + bhh0g[gg*256 + col];
            bp1[ct] = bih1g[gg*256 + col] + bhh1g[gg*256 + col];
        } else if (isN) {
            bp0[ct] = bih0g[512 + col];  bq0[ct] = bhh0g[512 + col];
            bp1[ct] = bih1g[512 + col];  bq1[ct] = bhh1g[512 + col];
        } else {
            bp0[ct] = b1g[col];  bp1[ct] = b2g[col];
        }
    }

    // device barrier across the group's 8 WGs
    auto gbar = [&](int bi) {
        __syncthreads();
        if (tid == 0) {
            __threadfence();                       // release (wbl2)
            atomicAdd(&ctrg[bi], 1u);
            int guard = 0;
            while (__hip_atomic_load(&ctrg[bi], __ATOMIC_RELAXED, __HIP_MEMORY_SCOPE_AGENT) < (uint32_t)NS) {
                __builtin_amdgcn_s_sleep(2);
                if (++guard > 10000000) break;     // degrade to wrong-answer, not hang
            }
            __threadfence();                       // acquire (inv)
        }
        __syncthreads();
    };
    auto AH = [&](u16 (*S)[264], int m16, int kt) -> bf16x8 {
        return *(const bf16x8*)&S[16 * m16 + l16][kt * 32 + kq8];
    };
    #define RZIDX(rz, mmh, ct, ml, q) ((((((rz)*2+(mmh))*2+(ct))*2+(ml))*4+(q))*64 + lane)

    f32x4 acc0[2][2], acc1[2][2];
    float loss = 0.0f;
    __syncthreads();

    #pragma unroll 1
    for (int t = 0; t < T_STEPS - 1; ++t) {
        // ================= Phase A: layer-0 gates =================
        if (isGate) {
            #pragma unroll
            for (int ct = 0; ct < 2; ++ct)
                #pragma unroll
                for (int ml = 0; ml < 2; ++ml) { acc0[ct][ml] = zero4(); acc1[ct][ml] = zero4(); }
            #pragma unroll
            for (int kt = 0; kt < 8; ++kt)
                #pragma unroll
                for (int ml = 0; ml < 2; ++ml) {
                    const bf16x8 a = AH(sh_h0, 2*mh + ml, kt);
                    if (isRZ) {
                        acc0[0][ml] = MFMA16(a, wf[kt],     acc0[0][ml]);
                        acc0[1][ml] = MFMA16(a, wf[8 + kt], acc0[1][ml]);
                    } else {           // n: gh0 -> acc1
                        acc1[0][ml] = MFMA16(a, wf[kt],     acc1[0][ml]);
                        acc1[1][ml] = MFMA16(a, wf[8 + kt], acc1[1][ml]);
                    }
                }
            #pragma unroll
            for (int ml = 0; ml < 2; ++ml) {   // gx0 (merged for r/z; separate acc0 for n)
                const bf16x8 ax = *(const bf16x8*)&sh_x[16*(2*mh + ml) + l16][kq8];
                acc0[0][ml] = MFMA16(ax, wf[16], acc0[0][ml]);
                acc0[1][ml] = MFMA16(ax, wf[17], acc0[1][ml]);
            }
        }
        __syncthreads();                                   // S1
        if (isRZ) {
            const int rz = w >> 1;
            #pragma unroll
            for (int ct = 0; ct < 2; ++ct)
                #pragma unroll
                for (int ml = 0; ml < 2; ++ml)
                    #pragma unroll
                    for (int q = 0; q < 4; ++q)
                        rzbuf[RZIDX(rz, mh, ct, ml, q)] = sigm(acc0[ct][ml][q] + bp0[ct]);
        }
        __syncthreads();                                   // S2
        if (isN) {
            #pragma unroll
            for (int ct = 0; ct < 2; ++ct)
                #pragma unroll
                for (int ml = 0; ml < 2; ++ml)
                    #pragma unroll
                    for (int q = 0; q < 4; ++q) {
                        const int row = 32*mh + 16*ml + kq*4 + q;
                        const int col = c*32 + ct*16 + l16;
                        const float r = rzbuf[RZIDX(0, mh, ct, ml, q)];
                        const float z = rzbuf[RZIDX(1, mh, ct, ml, q)];
                        const float n = tanh_fast(acc0[ct][ml][q] + bp0[ct] + r*(acc1[ct][ml][q] + bq0[ct]));
                        const float hold = bf2f(sh_h0[row][col]);
                        h0buf[row*256 + col] = f2bf((1.0f - z)*n + z*hold);
                    }
        }
        gbar(t * 3 + 0);                                   // B0
        {   // copy h0buf -> sh_h0 (full 64x256)
            const int row = tid >> 3, seg = tid & 7;
            const u16* src = h0buf + row*256 + seg*32;
            bf16x8 v0 = *(const bf16x8*)(src);
            bf16x8 v1 = *(const bf16x8*)(src + 8);
            bf16x8 v2 = *(const bf16x8*)(src + 16);
            bf16x8 v3 = *(const bf16x8*)(src + 24);
            *(bf16x8*)&sh_h0[row][seg*32]      = v0;
            *(bf16x8*)&sh_h0[row][seg*32 + 8]  = v1;
            *(bf16x8*)&sh_h0[row][seg*32 + 16] = v2;
            *(bf16x8*)&sh_h0[row][seg*32 + 24] = v3;
        }
        __syncthreads();                                   // S3
        // ================= Phase B: layer-1 gates (+ loss/x-stage on MLP waves) =================
        if (isGate) {
            #pragma unroll
            for (int ct = 0; ct < 2; ++ct)
                #pragma unroll
                for (int ml = 0; ml < 2; ++ml) { acc0[ct][ml] = zero4(); acc1[ct][ml] = zero4(); }
            #pragma unroll
            for (int kt = 0; kt < 8; ++kt)
                #pragma unroll
                for (int ml = 0; ml < 2; ++ml) {
                    const bf16x8 a1 = AH(sh_h1, 2*mh + ml, kt);        // gh1 (h1 old)
                    if (isRZ) {
                        acc0[0][ml] = MFMA16(a1, wf[18 + kt], acc0[0][ml]);
                        acc0[1][ml] = MFMA16(a1, wf[26 + kt], acc0[1][ml]);
                    } else {
                        acc1[0][ml] = MFMA16(a1, wf[18 + kt], acc1[0][ml]);
                        acc1[1][ml] = MFMA16(a1, wf[26 + kt], acc1[1][ml]);
                    }
                }
            const int gg = w >> 1;
            #pragma unroll
            for (int kt = 0; kt < 8; ++kt)
                #pragma unroll
                for (int ml = 0; ml < 2; ++ml) {
                    const bf16x8 a0 = AH(sh_h0, 2*mh + ml, kt);        // gx1 (h0 new)
                    const bf16x8 bx0 = *(const bf16x8*)&lds_wx1[(gg*16 + kt)*512 + lane*8];
                    const bf16x8 bx1 = *(const bf16x8*)&lds_wx1[(gg*16 + 8 + kt)*512 + lane*8];
                    acc0[0][ml] = MFMA16(a0, bx0, acc0[0][ml]);
                    acc0[1][ml] = MFMA16(a0, bx1, acc0[1][ml]);
                }
        } else {
            // loss for step t-1 (d3 partials all visible since B0)
            if (t > 0) {
                const int tidm = (w - 6) * 64 + lane;
                for (int it = tidm; it < 160; it += 128) {
                    const int rr = it / 20, col = it - rr * 20;
                    const int row = 8 * c + rr;
                    float s = sh_b3[col];
                    #pragma unroll
                    for (int sl = 0; sl < 8; ++sl) s += d3p[sl*2048 + row*32 + col];
                    const float y = data[(size_t)t * (BATCH*YDIM) + (size_t)(g*BS + row)*YDIM + col];
                    const float e = s - y;
                    loss += e * e;
                }
            }
            // stage x(t+1)
            if (t < T_STEPS - 2) {
                const int tidm = (w - 6) * 64 + lane;
                const float* xp = data + (size_t)(t + 1) * (BATCH*YDIM) + (size_t)(g*BS)*YDIM;
                for (int i = tidm; i < BS * YDIM; i += 128) {
                    int row = i / YDIM, col = i - row * YDIM;
                    sh_x[row][col] = f2bf(xp[i]);
                }
            }
        }
        __syncthreads();                                   // S4
        if (isRZ) {
            const int rz = w >> 1;
            #pragma unroll
            for (int ct = 0; ct < 2; ++ct)
                #pragma unroll
                for (int ml = 0; ml < 2; ++ml)
                    #pragma unroll
                    for (int q = 0; q < 4; ++q)
                        rzbuf[RZIDX(rz, mh, ct, ml, q)] = sigm(acc0[ct][ml][q] + bp1[ct]);
        }
        __syncthreads();                                   // S5
        if (isN) {
            #pragma unroll
            for (int ct = 0; ct < 2; ++ct)
                #pragma unroll
                for (int ml = 0; ml < 2; ++ml)
                    #pragma unroll
                    for (int q = 0; q < 4; ++q) {
                        const int row = 32*mh + 16*ml + kq*4 + q;
                        const int col = c*32 + ct*16 + l16;
                        const float r = rzbuf[RZIDX(0, mh, ct, ml, q)];
                        const float z = rzbuf[RZIDX(1, mh, ct, ml, q)];
                        const float n = tanh_fast(acc0[ct][ml][q] + bp1[ct] + r*(acc1[ct][ml][q] + bq1[ct]));
                        const float hold = bf2f(sh_h1[row][col]);
                        h1buf[row*256 + col] = f2bf((1.0f - z)*n + z*hold);
                    }
        }
        gbar(t * 3 + 1);                                   // B1
        {   // copy h1buf -> sh_h1
            const int row = tid >> 3, seg = tid & 7;
            const u16* src = h1buf + row*256 + seg*32;
            bf16x8 v0 = *(const bf16x8*)(src);
            bf16x8 v1 = *(const bf16x8*)(src + 8);
            bf16x8 v2 = *(const bf16x8*)(src + 16);
            bf16x8 v3 = *(const bf16x8*)(src + 24);
            *(bf16x8*)&sh_h1[row][seg*32]      = v0;
            *(bf16x8*)&sh_h1[row][seg*32 + 8]  = v1;
            *(bf16x8*)&sh_h1[row][seg*32 + 16] = v2;
            *(bf16x8*)&sh_h1[row][seg*32 + 24] = v3;
        }
        __syncthreads();                                   // S6
        // ================= Phase C: d1 = relu(h1new @ W1s) =================
        if (isMLP) {
            #pragma unroll
            for (int ct = 0; ct < 2; ++ct)
                #pragma unroll
                for (int ml = 0; ml < 2; ++ml) acc0[ct][ml] = zero4();
            #pragma unroll
            for (int kt = 0; kt < 8; ++kt)
                #pragma unroll
                for (int ml = 0; ml < 2; ++ml) {
                    const bf16x8 a = AH(sh_h1, 2*mh + ml, kt);
                    acc0[0][ml] = MFMA16(a, wf[kt],     acc0[0][ml]);
                    acc0[1][ml] = MFMA16(a, wf[8 + kt], acc0[1][ml]);
                }
            #pragma unroll
            for (int ct = 0; ct < 2; ++ct)
                #pragma unroll
                for (int ml = 0; ml < 2; ++ml)
                    #pragma unroll
                    for (int q = 0; q < 4; ++q) {
                        const int row = 32*mh + 16*ml + kq*4 + q;
                        const int col = c*32 + ct*16 + l16;
                        d1buf[row*256 + col] = f2bf(fmaxf(acc0[ct][ml][q] + bp0[ct], 0.0f));
                    }
        }
        gbar(t * 3 + 2);                                   // B2
        // ================= Phase D: d2 = relu(d1full @ W2s) =================
        if (isMLP) {
            #pragma unroll
            for (int ct = 0; ct < 2; ++ct)
                #pragma unroll
                for (int ml = 0; ml < 2; ++ml) acc0[ct][ml] = zero4();
            #pragma unroll
            for (int kt = 0; kt < 8; ++kt)
                #pragma unroll
                for (int ml = 0; ml < 2; ++ml) {
                    const bf16x8 ag = *(const bf16x8*)(d1buf + (16*(2*mh + ml) + l16)*256 + kt*32 + kq8);
                    acc0[0][ml] = MFMA16(ag, wf[16 + kt], acc0[0][ml]);
                    acc0[1][ml] = MFMA16(ag, wf[24 + kt], acc0[1][ml]);
                }
            #pragma unroll
            for (int ct = 0; ct < 2; ++ct)
                #pragma unroll
                for (int ml = 0; ml < 2; ++ml)
                    #pragma unroll
                    for (int q = 0; q < 4; ++q) {
                        const int row = 32*mh + 16*ml + kq*4 + q;
                        sh_d2[row][ct*16 + l16] = f2bf(fmaxf(acc0[ct][ml][q] + bp1[ct], 0.0f));
                    }
        }
        __syncthreads();                                   // S7
        // ================= Phase E: d3 K-partial (own d2 slice) =================
        if (isMLP) {
            f32x4 e[2][2];
            #pragma unroll
            for (int ct = 0; ct < 2; ++ct)
                #pragma unroll
                for (int ml = 0; ml < 2; ++ml) e[ct][ml] = zero4();
            #pragma unroll
            for (int ml = 0; ml < 2; ++ml) {
                const bf16x8 ad = *(const bf16x8*)&sh_d2[16*(2*mh + ml) + l16][kq8];
                e[0][ml] = MFMA16(ad, wf[32], e[0][ml]);
                e[1][ml] = MFMA16(ad, wf[33], e[1][ml]);
            }
            #pragma unroll
            for (int ct = 0; ct < 2; ++ct)
                #pragma unroll
                for (int ml = 0; ml < 2; ++ml)
                    #pragma unroll
                    for (int q = 0; q < 4; ++q) {
                        const int row = 32*mh + 16*ml + kq*4 + q;
                        d3p[(size_t)c*2048 + row*32 + ct*16 + l16] = e[ct][ml][q];
                    }
        }
    }

    // final loss for t = 254
    gbar(255 * 3);
    if (isMLP) {
        const int tidm = (w - 6) * 64 + lane;
        for (int it = tidm; it < 160; it += 128) {
            const int rr = it / 20, col = it - rr * 20;
            const int row = 8 * c + rr;
            float s = sh_b3[col];
            #pragma unroll
            for (int sl = 0; sl < 8; ++sl) s += d3p[sl*2048 + row*32 + col];
            const float y = data[(size_t)(T_STEPS - 1) * (BATCH*YDIM) + (size_t)(g*BS + row)*YDIM + col];
            const float e = s - y;
            loss += e * e;
        }
    }
    __syncthreads();
    #pragma unroll
    for (int s = 32; s > 0; s >>= 1) loss += __shfl_down(loss, s, 64);
    if (lane == 0 && isMLP) atomicAdd(out, loss);
}

extern "C" void kernel_launch(void* const* d_in, const int* in_sizes, int n_in,
                              void* d_out, int out_size, void* d_ws, size_t ws_size,
                              hipStream_t stream) {
    const float* data = (const float*)d_in[0];
    const float* Wih0 = (const float*)d_in[1];
    const float* Whh0 = (const float*)d_in[2];
    const float* bih0 = (const float*)d_in[3];
    const float* bhh0 = (const float*)d_in[4];
    const float* Wih1 = (const float*)d_in[5];
    const float* Whh1 = (const float*)d_in[6];
    const float* bih1 = (const float*)d_in[7];
    const float* bhh1 = (const float*)d_in[8];
    const float* W1   = (const float*)d_in[9];
    const float* b1   = (const float*)d_in[10];
    const float* W2   = (const float*)d_in[11];
    const float* b2   = (const float*)d_in[12];
    const float* W3   = (const float*)d_in[13];
    const float* b3   = (const float*)d_in[14];
    u16*   ws  = (u16*)d_ws;
    float* out = (float*)d_out;

    hipLaunchKernelGGL(prep_kernel, dim3(512), dim3(256), 0, stream,
                       Wih0, Whh0, Wih1, Whh1, W1, W2, W3, ws, out);
    hipLaunchKernelGGL(rnn_main, dim3(NWG), dim3(512), 0, stream,
                       data, bih0, bhh0, bih1, bhh1, b1, b2, b3, ws, out);
}

// Round 7
// 5635.271 us; speedup vs baseline: 2.2436x; 2.2436x over previous
//
#include <hip/hip_runtime.h>
#include <stdint.h>

typedef __attribute__((ext_vector_type(8))) short bf16x8;
typedef __attribute__((ext_vector_type(4))) float f32x4;
typedef __attribute__((ext_vector_type(2))) float f32x2;
typedef unsigned short u16;
typedef unsigned char u8;

#define MFMA16(a,b,c) __builtin_amdgcn_mfma_f32_16x16x32_bf16((a),(b),(c),0,0,0)

static constexpr int T_STEPS = 256;
static constexpr int BATCH   = 2048;
static constexpr int YDIM    = 20;
static constexpr int BS      = 16;            // batch rows per WG
static constexpr int NWG     = BATCH / BS;    // 128

// fp8 stream: 1536 blocks of 512 B, consumption order; 32 chunks of 48 blocks (24 KB).
// Block b, lane L, j: elem = W[row][k], row = rowbase + (L&15), k = kb*32 + (L>>4)*8 + j.
//  [0,384):    whh0 kb-major (48/kb: g*16+c)          chunks 0..7
//  [384,432):  wih0 (K pad 20->32)                    chunk 8
//  [432,1200): L1 per kb {whh1 48 | wih1 48}          chunks 9..24
//  [1200,1344): W1 kb-major 16/kb + 16 pad            chunks 25..27 (kb 0-2,3-5,6-7+pad)
//  [1344,1488): W2 same                               chunks 28..30
//  [1488,1536): W3 (16: kb*2+ct, rows pad 20->32) + 32 pad   chunk 31
static constexpr int NCHUNK    = 32;
static constexpr int CHUNK_B   = 48 * 512;            // 24576 bytes
static constexpr int STREAM_B  = NCHUNK * CHUNK_B;    // 786432 bytes
static constexpr int STREAM_U16= STREAM_B / 2;

__device__ __forceinline__ u16 f2bf(float x) {
    uint32_t u = __float_as_uint(x);
    u += 0x7FFFu + ((u >> 16) & 1u);
    return (u16)(u >> 16);
}
__device__ __forceinline__ float sigm(float x) { return 1.0f / (1.0f + __expf(-x)); }
__device__ __forceinline__ float tanh_fast(float x) {
    float s = __expf(-2.0f * fabsf(x));
    float r = (1.0f - s) / (1.0f + s);
    return copysignf(r, x);
}
__device__ __forceinline__ f32x4 zero4() { f32x4 v = {0.f, 0.f, 0.f, 0.f}; return v; }

// ---- stream value function (byte index -> weight value) ----
__device__ float stream_val(int i,
                            const float* __restrict__ Wih0, const float* __restrict__ Whh0,
                            const float* __restrict__ Wih1, const float* __restrict__ Whh1,
                            const float* __restrict__ W1,   const float* __restrict__ W2,
                            const float* __restrict__ W3) {
    int b = i >> 9, q = i & 511, L = q >> 3, j = q & 7;
    int l16 = L & 15, kq = L >> 4, k8 = kq * 8 + j;
    if (b < 384) {
        int kb = b / 48, r48 = b % 48;
        return Whh0[(r48 * 16 + l16) * 256 + kb * 32 + k8];
    } else if (b < 432) {
        int r48 = b - 384;
        return (k8 < YDIM) ? Wih0[(r48 * 16 + l16) * YDIM + k8] : 0.0f;
    } else if (b < 1200) {
        int rel = b - 432;
        int kb = rel / 96, sub = rel % 96;
        int h = sub / 48, r48 = sub % 48;
        int off = (r48 * 16 + l16) * 256 + kb * 32 + k8;
        return (h == 0) ? Whh1[off] : Wih1[off];
    } else if (b < 1344) {
        int rel = b - 1200;
        int kb = rel >> 4, c = rel & 15;
        return (kb < 8) ? W1[(c * 16 + l16) * 256 + kb * 32 + k8] : 0.0f;
    } else if (b < 1488) {
        int rel = b - 1344;
        int kb = rel >> 4, c = rel & 15;
        return (kb < 8) ? W2[(c * 16 + l16) * 256 + kb * 32 + k8] : 0.0f;
    } else {
        int rel = b - 1488;
        if (rel < 16) {
            int kb = rel >> 1, ct = rel & 1;
            int r3 = ct * 16 + l16;
            return (r3 < YDIM) ? W3[r3 * 256 + kb * 32 + k8] : 0.0f;
        }
        return 0.0f;
    }
}

__global__ void prep_kernel(const float* __restrict__ Wih0, const float* __restrict__ Whh0,
                            const float* __restrict__ Wih1, const float* __restrict__ Whh1,
                            const float* __restrict__ W1,   const float* __restrict__ W2,
                            const float* __restrict__ W3,   u16* __restrict__ ws,
                            float* __restrict__ out) {
    int tid = blockIdx.x * blockDim.x + threadIdx.x;
    if (tid == 0) out[0] = 0.0f;
    int stride = gridDim.x * blockDim.x;
    for (int i16 = tid; i16 < STREAM_U16; i16 += stride) {
        float a = stream_val(2 * i16,     Wih0, Whh0, Wih1, Whh1, W1, W2, W3);
        float b = stream_val(2 * i16 + 1, Wih0, Whh0, Wih1, Whh1, W1, W2, W3);
        // pack 2 x e4m3 (OCP, RNE) into low word; byte0 = a, byte1 = b
        ws[i16] = (u16)(__builtin_amdgcn_cvt_pk_fp8_f32(a, b, 0, false) & 0xffff);
    }
}

__global__ __launch_bounds__(512, 1) void rnn_main(
    const float* __restrict__ data,
    const float* __restrict__ bih0g, const float* __restrict__ bhh0g,
    const float* __restrict__ bih1g, const float* __restrict__ bhh1g,
    const float* __restrict__ b1g,  const float* __restrict__ b2g,
    const float* __restrict__ b3g,
    const u16* __restrict__ ws, float* __restrict__ out)
{
    __shared__ __align__(16) u8 wbuf[4][CHUNK_B];   // 96 KB fp8 chunk ring
    __shared__ u16 sh_h0[16][264];
    __shared__ u16 sh_h1[16][264];
    __shared__ u16 sh_d1[16][264];
    __shared__ u16 sh_d2[16][264];
    __shared__ u16 sh_x[16][40];

    const int tid  = threadIdx.x;
    const int w    = tid >> 6;           // wave 0..7
    const int lane = tid & 63;
    const int l16  = lane & 15;
    const int kq   = lane >> 4;
    const int kq8  = kq * 8;
    const int b0   = blockIdx.x * BS;
    const u8* wsb  = (const u8*)ws;

    // ---- init LDS ----
    for (int i = tid; i < 16 * 264; i += 512) { (&sh_h0[0][0])[i] = 0; (&sh_h1[0][0])[i] = 0; }
    for (int i = tid; i < 16 * 40;  i += 512) (&sh_x[0][0])[i] = 0;
    if (tid < BS * YDIM) sh_x[tid / YDIM][tid % YDIM] = f2bf(data[(size_t)b0 * YDIM + tid]);

    // ---- biases in registers ----
    float bR0[2], bZ0[2], bXN0[2], bHN0[2];
    float bR1[2], bZ1[2], bXN1[2], bHN1[2];
    float s1r[2], s2r[2];
    #pragma unroll
    for (int jj = 0; jj < 2; ++jj) {
        const int colb = (w + 8 * jj) * 16 + l16;
        bR0[jj]  = bih0g[colb] + bhh0g[colb];
        bZ0[jj]  = bih0g[colb + 256] + bhh0g[colb + 256];
        bXN0[jj] = bih0g[colb + 512];
        bHN0[jj] = bhh0g[colb + 512];
        bR1[jj]  = bih1g[colb] + bhh1g[colb];
        bZ1[jj]  = bih1g[colb + 256] + bhh1g[colb + 256];
        bXN1[jj] = bih1g[colb + 512];
        bHN1[jj] = bhh1g[colb + 512];
        s1r[jj]  = b1g[colb];
        s2r[jj]  = b2g[colb];
    }
    float s3r = 0.0f;
    { const int col = w * 16 + l16; if (w < 2 && col < YDIM) s3r = b3g[col]; }

    // ---- chunk pipeline ----
    int issPtr = 0, issBuf = 0, curBuf = 3;
    auto issueOne = [&]() {
        const u8* src = wsb + (size_t)issPtr * CHUNK_B;
        #pragma unroll
        for (int i = 0; i < 3; ++i) {
            __builtin_amdgcn_global_load_lds(
                (const __attribute__((address_space(1))) void*)(src + i * 8192 + tid * 16),
                (__attribute__((address_space(3))) void*)(&wbuf[issBuf][i * 8192 + tid * 16]),
                16, 0, 0);
        }
        issPtr = (issPtr == NCHUNK - 1) ? 0 : issPtr + 1;
        issBuf = (issBuf + 1) & 3;
    };
    // chunk top: wait current chunk (depth-3: 9 outstanding -> vmcnt(6)),
    // barrier, THEN issue k+3 (its ring slot was consumed before this barrier).
    auto CTOP = [&]() {
        asm volatile("s_waitcnt vmcnt(6) lgkmcnt(0)" ::: "memory");
        __builtin_amdgcn_sched_barrier(0);
        __builtin_amdgcn_s_barrier();
        __builtin_amdgcn_sched_barrier(0);
        issueOne();
        __builtin_amdgcn_sched_barrier(0);
        curBuf = (curBuf + 1) & 3;
    };
    // dequant a B-frag: 8 fp8 -> bf16x8 (HW cvt; f32->bf16 exact for 4-bit mantissa)
    auto BRdq = [&](int blk) -> bf16x8 {
        const uint32_t* p = (const uint32_t*)&wbuf[curBuf][blk * 512 + lane * 8];
        const uint32_t x0 = p[0], x1 = p[1];
        f32x2 f0 = __builtin_amdgcn_cvt_pk_f32_fp8(x0, false);
        f32x2 f1 = __builtin_amdgcn_cvt_pk_f32_fp8(x0, true);
        f32x2 f2 = __builtin_amdgcn_cvt_pk_f32_fp8(x1, false);
        f32x2 f3 = __builtin_amdgcn_cvt_pk_f32_fp8(x1, true);
        union { uint32_t u[4]; bf16x8 v; } r;
        asm("v_cvt_pk_bf16_f32 %0, %1, %2" : "=v"(r.u[0]) : "v"(f0.x), "v"(f0.y));
        asm("v_cvt_pk_bf16_f32 %0, %1, %2" : "=v"(r.u[1]) : "v"(f1.x), "v"(f1.y));
        asm("v_cvt_pk_bf16_f32 %0, %1, %2" : "=v"(r.u[2]) : "v"(f2.x), "v"(f2.y));
        asm("v_cvt_pk_bf16_f32 %0, %1, %2" : "=v"(r.u[3]) : "v"(f3.x), "v"(f3.y));
        return r.v;
    };
    auto AH = [&](u16 (*S)[264], int kt) -> bf16x8 {
        return *(const bf16x8*)&S[l16][kt * 32 + kq8];
    };

    f32x4 aR[2], aZ[2], aXN[2], aHN[2];
    auto zeroAcc = [&]() {
        #pragma unroll
        for (int jj = 0; jj < 2; ++jj) { aR[jj] = zero4(); aZ[jj] = zero4(); aXN[jj] = zero4(); aHN[jj] = zero4(); }
    };
    auto combine = [&](u16 (*H)[264], const float* cbR, const float* cbZ,
                       const float* cbXN, const float* cbHN) {
        #pragma unroll
        for (int jj = 0; jj < 2; ++jj) {
            const int colb = (w + 8 * jj) * 16 + l16;
            #pragma unroll
            for (int q = 0; q < 4; ++q) {
                const int row = kq * 4 + q;
                const float r = sigm(aR[jj][q] + cbR[jj]);
                const float z = sigm(aZ[jj][q] + cbZ[jj]);
                const float n = tanh_fast(aXN[jj][q] + cbXN[jj] + r * (aHN[jj][q] + cbHN[jj]));
                const float hp = __uint_as_float(((uint32_t)H[row][colb]) << 16);
                H[row][colb] = f2bf((1.0f - z) * n + z * hp);
            }
        }
    };

    // prologue: issue chunks 0,1,2
    issueOne(); issueOne(); issueOne();

    float loss = 0.0f;

    #pragma unroll 1
    for (int t = 0; t < T_STEPS - 1; ++t) {
        // ======== gh0: chunks 0..7 (whh0 kb) ========
        zeroAcc();
        #pragma unroll 1
        for (int kb = 0; kb < 8; ++kb) {
            CTOP();
            const bf16x8 a = AH(sh_h0, kb);
            #pragma unroll
            for (int jj = 0; jj < 2; ++jj) {
                aR[jj]  = MFMA16(a, BRdq(w + 8 * jj),      aR[jj]);
                aZ[jj]  = MFMA16(a, BRdq(16 + w + 8 * jj), aZ[jj]);
                aHN[jj] = MFMA16(a, BRdq(32 + w + 8 * jj), aHN[jj]);
            }
        }
        // ======== gx0: chunk 8 (wih0), then combine0 -> sh_h0 ========
        CTOP();
        {
            const bf16x8 ax = *(const bf16x8*)&sh_x[l16][kq8];
            #pragma unroll
            for (int jj = 0; jj < 2; ++jj) {
                aR[jj]  = MFMA16(ax, BRdq(w + 8 * jj),      aR[jj]);
                aZ[jj]  = MFMA16(ax, BRdq(16 + w + 8 * jj), aZ[jj]);
                aXN[jj] = MFMA16(ax, BRdq(32 + w + 8 * jj), aXN[jj]);
            }
        }
        combine(sh_h0, bR0, bZ0, bXN0, bHN0);
        // ======== L1: chunks 9..24 per kb {whh1 | wih1}; combine1 -> sh_h1 ========
        zeroAcc();
        #pragma unroll 1
        for (int j = 0; j < 8; ++j) {
            CTOP();                                  // whh1 kb j (A = sh_h1 old)
            {
                const bf16x8 a1 = AH(sh_h1, j);
                #pragma unroll
                for (int jj = 0; jj < 2; ++jj) {
                    aR[jj]  = MFMA16(a1, BRdq(w + 8 * jj),      aR[jj]);
                    aZ[jj]  = MFMA16(a1, BRdq(16 + w + 8 * jj), aZ[jj]);
                    aHN[jj] = MFMA16(a1, BRdq(32 + w + 8 * jj), aHN[jj]);
                }
            }
            CTOP();                                  // wih1 kb j (A = sh_h0 new)
            {
                const bf16x8 a0 = AH(sh_h0, j);
                #pragma unroll
                for (int jj = 0; jj < 2; ++jj) {
                    aR[jj]  = MFMA16(a0, BRdq(w + 8 * jj),      aR[jj]);
                    aZ[jj]  = MFMA16(a0, BRdq(16 + w + 8 * jj), aZ[jj]);
                    aXN[jj] = MFMA16(a0, BRdq(32 + w + 8 * jj), aXN[jj]);
                }
            }
        }
        combine(sh_h1, bR1, bZ1, bXN1, bHN1);
        // ======== W1: chunks 25..27 -> d1 = relu(h1 @ W1^T + b1) ========
        {
            f32x4 d0 = zero4(), d1v = zero4();
            #pragma unroll
            for (int cc = 0; cc < 3; ++cc) {
                CTOP();
                if (cc == 0 && t < T_STEPS - 2 && tid < BS * YDIM) {
                    const float* xp = data + (size_t)(t + 1) * (BATCH * YDIM) + (size_t)b0 * YDIM;
                    sh_x[tid / YDIM][tid % YDIM] = f2bf(xp[tid]);
                }
                #pragma unroll
                for (int kk = 0; kk < 3; ++kk) {
                    const int kb = cc * 3 + kk;
                    if (kb < 8) {
                        const bf16x8 a = AH(sh_h1, kb);
                        d0  = MFMA16(a, BRdq(kk * 16 + w),     d0);
                        d1v = MFMA16(a, BRdq(kk * 16 + 8 + w), d1v);
                    }
                }
            }
            #pragma unroll
            for (int jj = 0; jj < 2; ++jj) {
                const int col = (w + 8 * jj) * 16 + l16;
                const f32x4 dd = jj ? d1v : d0;
                #pragma unroll
                for (int q = 0; q < 4; ++q)
                    sh_d1[kq * 4 + q][col] = f2bf(fmaxf(dd[q] + s1r[jj], 0.0f));
            }
        }
        // ======== W2: chunks 28..30 -> d2 = relu(d1 @ W2^T + b2) ========
        {
            f32x4 d0 = zero4(), d1v = zero4();
            #pragma unroll
            for (int cc = 0; cc < 3; ++cc) {
                CTOP();                              // first barrier also publishes sh_d1
                #pragma unroll
                for (int kk = 0; kk < 3; ++kk) {
                    const int kb = cc * 3 + kk;
                    if (kb < 8) {
                        const bf16x8 a = AH(sh_d1, kb);
                        d0  = MFMA16(a, BRdq(kk * 16 + w),     d0);
                        d1v = MFMA16(a, BRdq(kk * 16 + 8 + w), d1v);
                    }
                }
            }
            #pragma unroll
            for (int jj = 0; jj < 2; ++jj) {
                const int col = (w + 8 * jj) * 16 + l16;
                const f32x4 dd = jj ? d1v : d0;
                #pragma unroll
                for (int q = 0; q < 4; ++q)
                    sh_d2[kq * 4 + q][col] = f2bf(fmaxf(dd[q] + s2r[jj], 0.0f));
            }
        }
        // ======== W3 + loss: chunk 31 ========
        CTOP();                                      // barrier publishes sh_d2
        if (w < 2) {
            f32x4 lacc = zero4();
            #pragma unroll
            for (int kb = 0; kb < 8; ++kb) {
                const bf16x8 a = AH(sh_d2, kb);
                lacc = MFMA16(a, BRdq(kb * 2 + w), lacc);
            }
            const int col = w * 16 + l16;
            if (col < YDIM) {
                const float* tp = data + (size_t)(t + 1) * (BATCH * YDIM) + (size_t)b0 * YDIM;
                #pragma unroll
                for (int q = 0; q < 4; ++q) {
                    const int row = kq * 4 + q;
                    const float d = (lacc[q] + s3r) - tp[row * YDIM + col];
                    loss += d * d;
                }
            }
        }
    }

    #pragma unroll
    for (int s = 32; s > 0; s >>= 1) loss += __shfl_down(loss, s, 64);
    if (lane == 0) atomicAdd(out, loss);
}

extern "C" void kernel_launch(void* const* d_in, const int* in_sizes, int n_in,
                              void* d_out, int out_size, void* d_ws, size_t ws_size,
                              hipStream_t stream) {
    const float* data = (const float*)d_in[0];
    const float* Wih0 = (const float*)d_in[1];
    const float* Whh0 = (const float*)d_in[2];
    const float* bih0 = (const float*)d_in[3];
    const float* bhh0 = (const float*)d_in[4];
    const float* Wih1 = (const float*)d_in[5];
    const float* Whh1 = (const float*)d_in[6];
    const float* bih1 = (const float*)d_in[7];
    const float* bhh1 = (const float*)d_in[8];
    const float* W1   = (const float*)d_in[9];
    const float* b1   = (const float*)d_in[10];
    const float* W2   = (const float*)d_in[11];
    const float* b2   = (const float*)d_in[12];
    const float* W3   = (const float*)d_in[13];
    const float* b3   = (const float*)d_in[14];
    u16*   ws  = (u16*)d_ws;
    float* out = (float*)d_out;

    hipLaunchKernelGGL(prep_kernel, dim3(512), dim3(256), 0, stream,
                       Wih0, Whh0, Wih1, Whh1, W1, W2, W3, ws, out);
    hipLaunchKernelGGL(rnn_main, dim3(NWG), dim3(512), 0, stream,
                       data, bih0, bhh0, bih1, bhh1, b1, b2, b3, ws, out);
}